// Round 2
// baseline (454.359 us; speedup 1.0000x reference)
//
#include <hip/hip_runtime.h>
#include <hip/hip_bf16.h>
#include <cstdint>
#include <cmath>

// ---------------- types / helpers ----------------
typedef int intx4 __attribute__((ext_vector_type(4)));

#define EPSQ 1e-5f

// async global->LDS, 16B per lane. LDS dest = wave-uniform base + lane*16.
__device__ __forceinline__ void async16(const void* g, void* l) {
  __builtin_amdgcn_global_load_lds(
      (const __attribute__((address_space(1))) unsigned int*)(uintptr_t)g,
      (__attribute__((address_space(3))) unsigned int*)(unsigned int)(uintptr_t)l,
      16, 0, 0);
}

__device__ __forceinline__ int q8(float v, float scale, float lo, float hi) {
  return (int)fminf(fmaxf(rintf(v * scale), lo), hi);
}

// Branchless exact-GELU via Abramowitz-Stegun 7.1.26 rational erf.
// |erf err| <= 1.5e-7 abs -> |h err| <= ~2.4e-6, ~4 orders below the int8
// quant step of h. ~15 fast VALU instrs vs ~40-instr branchy libm erff.
__device__ __forceinline__ float fast_gelu(float y) {
  const float t = y * 0.70710678118654752f;
  const float x = fabsf(t);
  const float u = __builtin_amdgcn_rcpf(__builtin_fmaf(0.3275911f, x, 1.0f));
  float p = __builtin_fmaf(1.061405429f, u, -1.453152027f);
  p = __builtin_fmaf(p, u, 1.421413741f);
  p = __builtin_fmaf(p, u, -0.284496736f);
  p = __builtin_fmaf(p, u, 0.254829592f);
  p = p * u;
  const float e = __expf(-x * x);                    // v_exp_f32 (native)
  const float erf_abs = __builtin_fmaf(-p, e, 1.0f); // 1 - p*e
  const float erf_t = copysignf(erf_abs, t);
  return 0.5f * y * (1.0f + erf_t);
}

// ---------------- init ----------------
__global__ void k_init(float* rowmax, double* sums) {
  int i = blockIdx.x * 256 + threadIdx.x;
  if (i < 16384) rowmax[i] = 0.0f;
  if (i < 2) sums[i] = 0.0;
}

// ---------------- abs-sum of 2x 4194304 fp32 (-> fp64 acc), both weights ----------
__global__ __launch_bounds__(256) void k_absmean2(const float* __restrict__ W1,
                                                  const float* __restrict__ W2,
                                                  double* __restrict__ sums) {
  __shared__ double wsum[4];
  const int tid = threadIdx.x;
  const int which = blockIdx.x >> 11;                 // 0: W1, 1: W2
  const float* __restrict__ W = which ? W2 : W1;
  const size_t base = ((size_t)(blockIdx.x & 2047) * 256 + tid) * 8;
  float4 a = *(const float4*)(W + base);
  float4 b = *(const float4*)(W + base + 4);
  float s = fabsf(a.x) + fabsf(a.y) + fabsf(a.z) + fabsf(a.w) +
            fabsf(b.x) + fabsf(b.y) + fabsf(b.z) + fabsf(b.w);
  double d = (double)s;
#pragma unroll
  for (int i = 1; i < 64; i <<= 1) d += __shfl_xor(d, i);
  const int lane = tid & 63, wave = tid >> 6;
  if (lane == 0) wsum[wave] = d;
  __syncthreads();
  if (tid == 0) atomicAdd(sums + which, wsum[0] + wsum[1] + wsum[2] + wsum[3]);
}

// ---------------- ternary weight quant (fp32 in) -> int8 {-1,0,1}, both weights ----
__global__ __launch_bounds__(256) void k_quantw2(const float* __restrict__ W1,
                                                 const float* __restrict__ W2,
                                                 signed char* __restrict__ W1Q,
                                                 signed char* __restrict__ W2Q,
                                                 const double* __restrict__ sums) {
  const int which = blockIdx.x >> 11;
  const float* __restrict__ W = which ? W2 : W1;
  signed char* __restrict__ WQ = which ? W2Q : W1Q;
  const float s = fmaxf((float)(sums[which] * (1.0 / 4194304.0)), EPSQ);
  const float inv_s = 1.0f / s;
  const size_t base = ((size_t)(blockIdx.x & 2047) * 256 + threadIdx.x) * 8;
  float4 a = *(const float4*)(W + base);
  float4 b = *(const float4*)(W + base + 4);
  float v[8] = {a.x, a.y, a.z, a.w, b.x, b.y, b.z, b.w};
  unsigned int lo = 0, hi = 0;
#pragma unroll
  for (int j = 0; j < 4; ++j) {
    lo |= ((unsigned int)(q8(v[j], inv_s, -1.f, 1.f) & 0xff)) << (8 * j);
    hi |= ((unsigned int)(q8(v[4 + j], inv_s, -1.f, 1.f) & 0xff)) << (8 * j);
  }
  uint2 o; o.x = lo; o.y = hi;
  *(uint2*)(WQ + base) = o;
}

// ---------------- per-token int8 act quant of x (fp32 in, 1024/row) ----------------
__global__ __launch_bounds__(256) void k_quantx(const float* __restrict__ X,
                                                signed char* __restrict__ XQ,
                                                float* __restrict__ dqx) {
  __shared__ float wmax[4];
  const int row = blockIdx.x, tid = threadIdx.x;
  const size_t base = (size_t)row * 1024 + tid * 4;
  float4 a = *(const float4*)(X + base);
  float m = fmaxf(fmaxf(fabsf(a.x), fabsf(a.y)), fmaxf(fabsf(a.z), fabsf(a.w)));
#pragma unroll
  for (int i = 1; i < 64; i <<= 1) m = fmaxf(m, __shfl_xor(m, i));
  const int lane = tid & 63, wave = tid >> 6;
  if (lane == 0) wmax[wave] = m;
  __syncthreads();
  m = fmaxf(fmaxf(wmax[0], wmax[1]), fmaxf(wmax[2], wmax[3]));
  m = fmaxf(m, EPSQ);
  const float scale = 127.f / m;
  if (tid == 0) dqx[row] = m * (1.f / 127.f);
  unsigned int p = ((unsigned int)(q8(a.x, scale, -128.f, 127.f) & 0xff)) |
                   ((unsigned int)(q8(a.y, scale, -128.f, 127.f) & 0xff) << 8) |
                   ((unsigned int)(q8(a.z, scale, -128.f, 127.f) & 0xff) << 16) |
                   ((unsigned int)(q8(a.w, scale, -128.f, 127.f) & 0xff) << 24);
  *(unsigned int*)(XQ + base) = p;
}

// ---------------- shared GEMM mainloop: C[128x128] = A[128xK] * B[128xK]^T ----------
// int8 operands, int32 exact accumulation via mfma_i32_16x16x64_i8.
// A,B row-major i8, row length KB bytes. 4 waves (2x2), each 64x64 via 4x4 MFMA.
// LDS tiles 128x128 i8 (16 KB each), XOR-swizzled 16B granules (physical granule g
// at row r holds logical granule g^(r&7)) — byte-identical addressing to the
// R5-verified bf16 mainloop; only element width and MFMA opcode change.
template <int KB>
__device__ __forceinline__ void gemm_mainloop(const signed char* __restrict__ A,
                                              const signed char* __restrict__ B,
                                              int bm, int bn, int tid, char* lds,
                                              intx4 (&acc)[4][4]) {
  const int wave = tid >> 6, lane = tid & 63;
  const int wm = wave >> 1, wn = wave & 1;
  const int kq = lane >> 4, lc = lane & 15;

  size_t ag[4], bg[4];
#pragma unroll
  for (int i = 0; i < 4; ++i) {
    int gidx = i * 256 + tid;
    int r = gidx >> 3, g = gidx & 7;
    int gs = g ^ (r & 7);
    ag[i] = (size_t)(bm * 128 + r) * KB + gs * 16;
    bg[i] = (size_t)(bn * 128 + r) * KB + gs * 16;
  }
  int aoff[2][4], boff[2][4];
#pragma unroll
  for (int ks = 0; ks < 2; ++ks) {
#pragma unroll
    for (int t = 0; t < 4; ++t) {
      int ra = wm * 64 + t * 16 + lc;
      aoff[ks][t] = ra * 128 + (((ks * 4 + kq) ^ (ra & 7)) << 4);
      int rb = wn * 64 + t * 16 + lc;
      boff[ks][t] = 16384 + rb * 128 + (((ks * 4 + kq) ^ (rb & 7)) << 4);
    }
  }
#pragma unroll
  for (int ti = 0; ti < 4; ++ti)
#pragma unroll
    for (int tj = 0; tj < 4; ++tj) {
      intx4 z = {0, 0, 0, 0};
      acc[ti][tj] = z;
    }

  for (int kt = 0; kt < KB / 128; ++kt) {
    __syncthreads();
    const int k0 = kt * 128;
#pragma unroll
    for (int i = 0; i < 4; ++i) {
      async16(A + ag[i] + k0, lds + i * 4096 + wave * 1024);
      async16(B + bg[i] + k0, lds + 16384 + i * 4096 + wave * 1024);
    }
    asm volatile("s_waitcnt vmcnt(0)" ::: "memory");
    __syncthreads();
#pragma unroll
    for (int ks = 0; ks < 2; ++ks) {
      intx4 af[4], bfr[4];
#pragma unroll
      for (int t = 0; t < 4; ++t) af[t] = *(const intx4*)(lds + aoff[ks][t]);
#pragma unroll
      for (int t = 0; t < 4; ++t) bfr[t] = *(const intx4*)(lds + boff[ks][t]);
#pragma unroll
      for (int ti = 0; ti < 4; ++ti)
#pragma unroll
        for (int tj = 0; tj < 4; ++tj)
          acc[ti][tj] =
              __builtin_amdgcn_mfma_i32_16x16x64_i8(af[ti], bfr[tj], acc[ti][tj], 0, 0, 0);
    }
  }
}

// ---------------- GEMM1 + dequant + exact GELU + fp32 h store + row |h| max ---------
__global__ __launch_bounds__(256) void k_gemm1(const signed char* __restrict__ A,
                                               const signed char* __restrict__ B,
                                               const float* __restrict__ dqx,
                                               const double* __restrict__ sums,
                                               float* __restrict__ H,
                                               float* __restrict__ rowmax) {
  __shared__ __attribute__((aligned(16))) char lds[32768];
  __shared__ float smax[128];
  const int tid = threadIdx.x;
  const int bm = blockIdx.x, bn = blockIdx.y;
  if (tid < 128) smax[tid] = 0.0f;

  intx4 acc[4][4];
  gemm_mainloop<1024>(A, B, bm, bn, tid, lds, acc);

  const int wave = tid >> 6, lane = tid & 63;
  const int wm = wave >> 1, wn = wave & 1;
  const int kq = lane >> 4, lc = lane & 15;
  const float s1 = fmaxf((float)(sums[0] * (1.0 / 4194304.0)), EPSQ);
#pragma unroll
  for (int ti = 0; ti < 4; ++ti) {
#pragma unroll
    for (int r = 0; r < 4; ++r) {
      const int lrow = wm * 64 + ti * 16 + kq * 4 + r;
      const int crow = bm * 128 + lrow;  // chunk-local row
      const float f = s1 * dqx[crow];
      float mx = 0.f;
#pragma unroll
      for (int tj = 0; tj < 4; ++tj) {
        const int gcol = bn * 128 + wn * 64 + tj * 16 + lc;
        float y = (float)acc[ti][tj][r] * f;
        float h = fast_gelu(y);
        H[(size_t)crow * 4096 + gcol] = h;
        mx = fmaxf(mx, fabsf(h));
      }
      atomicMax((unsigned int*)&smax[lrow], __float_as_uint(mx));
    }
  }
  __syncthreads();
  if (tid < 128)
    atomicMax((unsigned int*)&rowmax[bm * 128 + tid], __float_as_uint(smax[tid]));
}

// ---------------- quantize h (fp32, chunk-local) -> int8 (scale from rowmax) --------
__global__ __launch_bounds__(256) void k_quanth(const float* __restrict__ H,
                                                const float* __restrict__ rowmax,
                                                signed char* __restrict__ HQ) {
  const size_t gid = (size_t)blockIdx.x * 256 + threadIdx.x;
  const size_t base = gid * 4;
  const int row = (int)(base >> 12);  // 4096 per row
  const float m = fmaxf(rowmax[row], EPSQ);
  const float scale = 127.f / m;
  float4 h = *(const float4*)(H + base);
  unsigned int p = ((unsigned int)(q8(h.x, scale, -128.f, 127.f) & 0xff)) |
                   ((unsigned int)(q8(h.y, scale, -128.f, 127.f) & 0xff) << 8) |
                   ((unsigned int)(q8(h.z, scale, -128.f, 127.f) & 0xff) << 16) |
                   ((unsigned int)(q8(h.w, scale, -128.f, 127.f) & 0xff) << 24);
  *(unsigned int*)(HQ + base) = p;
}

// ---------------- GEMM2 + dequant -> fp32 out (global rows, single launch) ----------
__global__ __launch_bounds__(256) void k_gemm2(const signed char* __restrict__ A,
                                               const signed char* __restrict__ B,
                                               const float* __restrict__ rowmax,
                                               const double* __restrict__ sums,
                                               float* __restrict__ OUT) {
  __shared__ __attribute__((aligned(16))) char lds[32768];
  const int tid = threadIdx.x;
  const int bm = blockIdx.x, bn = blockIdx.y;

  intx4 acc[4][4];
  gemm_mainloop<4096>(A, B, bm, bn, tid, lds, acc);

  const int wave = tid >> 6, lane = tid & 63;
  const int wm = wave >> 1, wn = wave & 1;
  const int kq = lane >> 4, lc = lane & 15;
  const float s2 = fmaxf((float)(sums[0] * (1.0 / 4194304.0)), EPSQ);
#pragma unroll
  for (int ti = 0; ti < 4; ++ti) {
#pragma unroll
    for (int r = 0; r < 4; ++r) {
      const int crow = bm * 128 + wm * 64 + ti * 16 + kq * 4 + r;
      const float dqh = fmaxf(rowmax[crow], EPSQ) * (1.f / 127.f);
      const float f = s2 * dqh;
#pragma unroll
      for (int tj = 0; tj < 4; ++tj) {
        const int gcol = bn * 128 + wn * 64 + tj * 16 + lc;
        OUT[(size_t)crow * 1024 + gcol] = (float)acc[ti][tj][r] * f;
      }
    }
  }
}

// ---------------- launcher ----------------
extern "C" void kernel_launch(void* const* d_in, const int* in_sizes, int n_in,
                              void* d_out, int out_size, void* d_ws, size_t ws_size,
                              hipStream_t stream) {
  const float* X  = (const float*)d_in[0];  // [16384][1024] fp32
  const float* W1 = (const float*)d_in[1];  // [4096][1024]  fp32
  const float* W2 = (const float*)d_in[2];  // [1024][4096]  fp32
  float* OUT = (float*)d_out;               // [16384][1024] fp32 (64 MB)

  char* ws = (char*)d_ws;
  // Fixed-footprint region: 9 MB misc + 64 MB full HQ = 73 MB
  signed char* W1Q = (signed char*)(ws);                            // 4 MB
  signed char* W2Q = (signed char*)(ws + (4u << 20));               // 4 MB
  float* DQX       = (float*)(ws + (8u << 20));                     // 64 KB
  float* ROWMAX    = (float*)(ws + (8u << 20) + 65536);             // 64 KB
  double* SUMS     = (double*)(ws + (8u << 20) + 131072);           // 16 B
  signed char* HQ  = (signed char*)(ws + (9u << 20));               // 64 MB (FULL 16384x4096)
  const size_t fixed = 73u << 20;
  float* H = (float*)(ws + fixed);                                  // R*16384 B (chunk fp32 scratch)

  // XQ (16384x1024 i8 = 16 MB) aliases the TOP 16 MB of fp32 d_out (64 MB).
  // New schedule: OUT is written ONLY by the single final gemm2 launch, which
  // runs after every gemm1 (all XQ reads) has completed in stream order — the
  // alias is strictly read-then-overwrite. OUT writes re-cover all 64 MB.
  signed char* XQ = (signed char*)((char*)d_out + 50331648ull);

  // Pick largest row-chunk R for the fp32 H scratch: need fixed + R*16384 bytes.
  // (HQ is now full-size, so gemm2 launches ONCE over all rows at full grid:
  //  (128,8)=1024 wgs = 4 wg/CU, vs 2 wg/CU when chunked — occupancy fix.)
  int R = 128;
  const int cands[8] = {16384, 8192, 4096, 2048, 1024, 512, 256, 128};
  for (int i = 0; i < 8; ++i) {
    if (fixed + (size_t)cands[i] * 16384ull <= ws_size) { R = cands[i]; break; }
  }

  hipLaunchKernelGGL(k_init, dim3(64), dim3(256), 0, stream, ROWMAX, SUMS);
  hipLaunchKernelGGL(k_absmean2, dim3(4096), dim3(256), 0, stream, W1, W2, SUMS);
  hipLaunchKernelGGL(k_quantw2, dim3(4096), dim3(256), 0, stream, W1, W2, W1Q, W2Q, SUMS);
  hipLaunchKernelGGL(k_quantx, dim3(16384), dim3(256), 0, stream, X, XQ, DQX);

  const int nchunk = 16384 / R;
  for (int c = 0; c < nchunk; ++c) {
    const int row0 = c * R;
    hipLaunchKernelGGL(k_gemm1, dim3(R / 128, 32), dim3(256), 0, stream,
                       XQ + (size_t)row0 * 1024, W1Q, DQX + row0, SUMS, H, ROWMAX + row0);
    hipLaunchKernelGGL(k_quanth, dim3(R * 4), dim3(256), 0, stream,
                       H, ROWMAX + row0, HQ + (size_t)row0 * 4096);
  }
  // Single full-size GEMM2: grid 1024 wgs -> 4 wg/CU (was 2 wg/CU per-chunk).
  hipLaunchKernelGGL(k_gemm2, dim3(128, 8), dim3(256), 0, stream,
                     HQ, W2Q, ROWMAX, SUMS + 1, OUT);
}

// Round 3
// 452.939 us; speedup vs baseline: 1.0031x; 1.0031x over previous
//
#include <hip/hip_runtime.h>
#include <hip/hip_bf16.h>
#include <cstdint>
#include <cmath>

// ---------------- types / helpers ----------------
typedef int intx4 __attribute__((ext_vector_type(4)));
typedef short shortx8 __attribute__((ext_vector_type(8)));

#define EPSQ 1e-5f

// async global->LDS, 16B per lane. LDS dest = wave-uniform base + lane*16.
__device__ __forceinline__ void async16(const void* g, void* l) {
  __builtin_amdgcn_global_load_lds(
      (const __attribute__((address_space(1))) unsigned int*)(uintptr_t)g,
      (__attribute__((address_space(3))) unsigned int*)(unsigned int)(uintptr_t)l,
      16, 0, 0);
}

__device__ __forceinline__ int q8(float v, float scale, float lo, float hi) {
  return (int)fminf(fmaxf(rintf(v * scale), lo), hi);
}

// Branchless exact-GELU via Abramowitz-Stegun 7.1.26 rational erf.
// |erf err| <= 1.5e-7 abs -> |h err| <= ~2.4e-6, ~4 orders below the int8
// quant step of h. ~15 fast VALU instrs vs ~40-instr branchy libm erff.
__device__ __forceinline__ float fast_gelu(float y) {
  const float t = y * 0.70710678118654752f;
  const float x = fabsf(t);
  const float u = __builtin_amdgcn_rcpf(__builtin_fmaf(0.3275911f, x, 1.0f));
  float p = __builtin_fmaf(1.061405429f, u, -1.453152027f);
  p = __builtin_fmaf(p, u, 1.421413741f);
  p = __builtin_fmaf(p, u, -0.284496736f);
  p = __builtin_fmaf(p, u, 0.254829592f);
  p = p * u;
  const float e = __expf(-x * x);                    // v_exp_f32 (native)
  const float erf_abs = __builtin_fmaf(-p, e, 1.0f); // 1 - p*e
  const float erf_t = copysignf(erf_abs, t);
  return 0.5f * y * (1.0f + erf_t);
}

// ---------------- init ----------------
__global__ void k_init(float* rowmax, double* sums) {
  int i = blockIdx.x * 256 + threadIdx.x;
  if (i < 16384) rowmax[i] = 0.0f;
  if (i < 2) sums[i] = 0.0;
}

// ---------------- abs-sum of 2x 4194304 fp32 (-> fp64 acc), both weights ----------
__global__ __launch_bounds__(256) void k_absmean2(const float* __restrict__ W1,
                                                  const float* __restrict__ W2,
                                                  double* __restrict__ sums) {
  __shared__ double wsum[4];
  const int tid = threadIdx.x;
  const int which = blockIdx.x >> 11;                 // 0: W1, 1: W2
  const float* __restrict__ W = which ? W2 : W1;
  const size_t base = ((size_t)(blockIdx.x & 2047) * 256 + tid) * 8;
  float4 a = *(const float4*)(W + base);
  float4 b = *(const float4*)(W + base + 4);
  float s = fabsf(a.x) + fabsf(a.y) + fabsf(a.z) + fabsf(a.w) +
            fabsf(b.x) + fabsf(b.y) + fabsf(b.z) + fabsf(b.w);
  double d = (double)s;
#pragma unroll
  for (int i = 1; i < 64; i <<= 1) d += __shfl_xor(d, i);
  const int lane = tid & 63, wave = tid >> 6;
  if (lane == 0) wsum[wave] = d;
  __syncthreads();
  if (tid == 0) atomicAdd(sums + which, wsum[0] + wsum[1] + wsum[2] + wsum[3]);
}

// ---------------- ternary weight quant (fp32 in) -> int8 {-1,0,1}, both weights ----
__global__ __launch_bounds__(256) void k_quantw2(const float* __restrict__ W1,
                                                 const float* __restrict__ W2,
                                                 signed char* __restrict__ W1Q,
                                                 signed char* __restrict__ W2Q,
                                                 const double* __restrict__ sums) {
  const int which = blockIdx.x >> 11;
  const float* __restrict__ W = which ? W2 : W1;
  signed char* __restrict__ WQ = which ? W2Q : W1Q;
  const float s = fmaxf((float)(sums[which] * (1.0 / 4194304.0)), EPSQ);
  const float inv_s = 1.0f / s;
  const size_t base = ((size_t)(blockIdx.x & 2047) * 256 + threadIdx.x) * 8;
  float4 a = *(const float4*)(W + base);
  float4 b = *(const float4*)(W + base + 4);
  float v[8] = {a.x, a.y, a.z, a.w, b.x, b.y, b.z, b.w};
  unsigned int lo = 0, hi = 0;
#pragma unroll
  for (int j = 0; j < 4; ++j) {
    lo |= ((unsigned int)(q8(v[j], inv_s, -1.f, 1.f) & 0xff)) << (8 * j);
    hi |= ((unsigned int)(q8(v[4 + j], inv_s, -1.f, 1.f) & 0xff)) << (8 * j);
  }
  uint2 o; o.x = lo; o.y = hi;
  *(uint2*)(WQ + base) = o;
}

// ---------------- per-token int8 act quant of x (fp32 in, 1024/row) ----------------
__global__ __launch_bounds__(256) void k_quantx(const float* __restrict__ X,
                                                signed char* __restrict__ XQ,
                                                float* __restrict__ dqx) {
  __shared__ float wmax[4];
  const int row = blockIdx.x, tid = threadIdx.x;
  const size_t base = (size_t)row * 1024 + tid * 4;
  float4 a = *(const float4*)(X + base);
  float m = fmaxf(fmaxf(fabsf(a.x), fabsf(a.y)), fmaxf(fabsf(a.z), fabsf(a.w)));
#pragma unroll
  for (int i = 1; i < 64; i <<= 1) m = fmaxf(m, __shfl_xor(m, i));
  const int lane = tid & 63, wave = tid >> 6;
  if (lane == 0) wmax[wave] = m;
  __syncthreads();
  m = fmaxf(fmaxf(wmax[0], wmax[1]), fmaxf(wmax[2], wmax[3]));
  m = fmaxf(m, EPSQ);
  const float scale = 127.f / m;
  if (tid == 0) dqx[row] = m * (1.f / 127.f);
  unsigned int p = ((unsigned int)(q8(a.x, scale, -128.f, 127.f) & 0xff)) |
                   ((unsigned int)(q8(a.y, scale, -128.f, 127.f) & 0xff) << 8) |
                   ((unsigned int)(q8(a.z, scale, -128.f, 127.f) & 0xff) << 16) |
                   ((unsigned int)(q8(a.w, scale, -128.f, 127.f) & 0xff) << 24);
  *(unsigned int*)(XQ + base) = p;
}

// ---------------- shared GEMM mainloop: C[128x128] = A[128xK] * B[128xK]^T ----------
// int8 operands, int32 exact accumulation via mfma_i32_16x16x64_i8.
// A,B row-major i8, row length KB bytes. 4 waves (2x2), each 64x64 via 4x4 MFMA.
// LDS tiles 128x128 i8 (16 KB each), XOR-swizzled 16B granules (physical granule g
// at row r holds logical granule g^(r&7)) — byte-identical addressing to the
// R5-verified bf16 mainloop; only element width and MFMA opcode change.
template <int KB>
__device__ __forceinline__ void gemm_mainloop(const signed char* __restrict__ A,
                                              const signed char* __restrict__ B,
                                              int bm, int bn, int tid, char* lds,
                                              intx4 (&acc)[4][4]) {
  const int wave = tid >> 6, lane = tid & 63;
  const int wm = wave >> 1, wn = wave & 1;
  const int kq = lane >> 4, lc = lane & 15;

  size_t ag[4], bg[4];
#pragma unroll
  for (int i = 0; i < 4; ++i) {
    int gidx = i * 256 + tid;
    int r = gidx >> 3, g = gidx & 7;
    int gs = g ^ (r & 7);
    ag[i] = (size_t)(bm * 128 + r) * KB + gs * 16;
    bg[i] = (size_t)(bn * 128 + r) * KB + gs * 16;
  }
  int aoff[2][4], boff[2][4];
#pragma unroll
  for (int ks = 0; ks < 2; ++ks) {
#pragma unroll
    for (int t = 0; t < 4; ++t) {
      int ra = wm * 64 + t * 16 + lc;
      aoff[ks][t] = ra * 128 + (((ks * 4 + kq) ^ (ra & 7)) << 4);
      int rb = wn * 64 + t * 16 + lc;
      boff[ks][t] = 16384 + rb * 128 + (((ks * 4 + kq) ^ (rb & 7)) << 4);
    }
  }
#pragma unroll
  for (int ti = 0; ti < 4; ++ti)
#pragma unroll
    for (int tj = 0; tj < 4; ++tj) {
      intx4 z = {0, 0, 0, 0};
      acc[ti][tj] = z;
    }

  for (int kt = 0; kt < KB / 128; ++kt) {
    __syncthreads();
    const int k0 = kt * 128;
#pragma unroll
    for (int i = 0; i < 4; ++i) {
      async16(A + ag[i] + k0, lds + i * 4096 + wave * 1024);
      async16(B + bg[i] + k0, lds + 16384 + i * 4096 + wave * 1024);
    }
    asm volatile("s_waitcnt vmcnt(0)" ::: "memory");
    __syncthreads();
#pragma unroll
    for (int ks = 0; ks < 2; ++ks) {
      intx4 af[4], bfr[4];
#pragma unroll
      for (int t = 0; t < 4; ++t) af[t] = *(const intx4*)(lds + aoff[ks][t]);
#pragma unroll
      for (int t = 0; t < 4; ++t) bfr[t] = *(const intx4*)(lds + boff[ks][t]);
#pragma unroll
      for (int ti = 0; ti < 4; ++ti)
#pragma unroll
        for (int tj = 0; tj < 4; ++tj)
          acc[ti][tj] =
              __builtin_amdgcn_mfma_i32_16x16x64_i8(af[ti], bfr[tj], acc[ti][tj], 0, 0, 0);
    }
  }
}

// ---------------- GEMM1 + dequant + exact GELU + int16 block-scaled h store --------
// h stored as round(h * 32767 / m_blk) int16, with m_blk = per-(row,128-col-block)
// max|h| (the block's smax). Halves H HBM traffic vs fp32 (256MB vs 512MB round
// trip). Dequant err <= m_blk/65534 -> <= 0.002 int8-LSB in scaled units.
__global__ __launch_bounds__(256) void k_gemm1(const signed char* __restrict__ A,
                                               const signed char* __restrict__ B,
                                               const float* __restrict__ dqx,
                                               const double* __restrict__ sums,
                                               short* __restrict__ HS,
                                               float* __restrict__ mblk,
                                               float* __restrict__ rowmax) {
  __shared__ __attribute__((aligned(16))) char lds[32768];
  const int tid = threadIdx.x;
  const int bm = blockIdx.x, bn = blockIdx.y;

  intx4 acc[4][4];
  gemm_mainloop<1024>(A, B, bm, bn, tid, lds, acc);

  const int wave = tid >> 6, lane = tid & 63;
  const int wm = wave >> 1, wn = wave & 1;
  const int kq = lane >> 4, lc = lane & 15;
  const float s1 = fmaxf((float)(sums[0] * (1.0 / 4194304.0)), EPSQ);

  // reuse mainloop LDS (dead now) for the per-row block-max array
  __syncthreads();
  float* smax = (float*)lds;
  if (tid < 128) smax[tid] = 0.0f;
  __syncthreads();

  // pass 1: dequant + GELU, stash h bits back into acc (zero extra VGPR),
  // accumulate per-row block max.
#pragma unroll
  for (int ti = 0; ti < 4; ++ti) {
#pragma unroll
    for (int r = 0; r < 4; ++r) {
      const int lrow = wm * 64 + ti * 16 + kq * 4 + r;
      const int crow = bm * 128 + lrow;  // chunk-local row
      const float f = s1 * dqx[crow];
      float mx = 0.f;
#pragma unroll
      for (int tj = 0; tj < 4; ++tj) {
        float y = (float)acc[ti][tj][r] * f;
        float h = fast_gelu(y);
        acc[ti][tj][r] = (int)__float_as_uint(h);
        mx = fmaxf(mx, fabsf(h));
      }
      atomicMax((unsigned int*)&smax[lrow], __float_as_uint(mx));
    }
  }
  __syncthreads();
  if (tid < 128) {
    mblk[(size_t)(bm * 128 + tid) * 32 + bn] = smax[tid];
    atomicMax((unsigned int*)&rowmax[bm * 128 + tid], __float_as_uint(smax[tid]));
  }

  // pass 2: int16 block-scaled store.
#pragma unroll
  for (int ti = 0; ti < 4; ++ti) {
#pragma unroll
    for (int r = 0; r < 4; ++r) {
      const int lrow = wm * 64 + ti * 16 + kq * 4 + r;
      const int crow = bm * 128 + lrow;
      const float sc = 32767.0f / fmaxf(smax[lrow], 1e-30f);
#pragma unroll
      for (int tj = 0; tj < 4; ++tj) {
        const int gcol = bn * 128 + wn * 64 + tj * 16 + lc;
        float h = __uint_as_float((unsigned int)acc[ti][tj][r]);
        int v = (int)fminf(fmaxf(rintf(h * sc), -32767.f), 32767.f);
        HS[(size_t)crow * 4096 + gcol] = (short)v;
      }
    }
  }
}

// ---------------- requantize h: int16 (block scale) -> int8 (global row scale) -----
__global__ __launch_bounds__(256) void k_quanth(const short* __restrict__ HS,
                                                const float* __restrict__ mblk,
                                                const float* __restrict__ rowmax,
                                                signed char* __restrict__ HQ) {
  const size_t gid = (size_t)blockIdx.x * 256 + threadIdx.x;
  const size_t base = gid * 8;              // 8 int16 per thread, all in one block
  const int row = (int)(base >> 12);        // 4096 per row
  const int blk = (int)((base >> 7) & 31);  // 128-col block index
  const float m = fmaxf(rowmax[row], EPSQ);
  const float fb = mblk[(size_t)row * 32 + blk] * (127.0f / 32767.0f) / m;
  shortx8 s = *(const shortx8*)(HS + base);
  unsigned int lo = 0, hi = 0;
#pragma unroll
  for (int j = 0; j < 4; ++j) {
    lo |= ((unsigned int)(q8((float)s[j], fb, -128.f, 127.f) & 0xff)) << (8 * j);
    hi |= ((unsigned int)(q8((float)s[4 + j], fb, -128.f, 127.f) & 0xff)) << (8 * j);
  }
  uint2 o; o.x = lo; o.y = hi;
  *(uint2*)(HQ + base) = o;
}

// ---------------- GEMM2 + dequant -> fp32 out (global rows, single launch) ----------
__global__ __launch_bounds__(256) void k_gemm2(const signed char* __restrict__ A,
                                               const signed char* __restrict__ B,
                                               const float* __restrict__ rowmax,
                                               const double* __restrict__ sums,
                                               float* __restrict__ OUT) {
  __shared__ __attribute__((aligned(16))) char lds[32768];
  const int tid = threadIdx.x;
  const int bm = blockIdx.x, bn = blockIdx.y;

  intx4 acc[4][4];
  gemm_mainloop<4096>(A, B, bm, bn, tid, lds, acc);

  const int wave = tid >> 6, lane = tid & 63;
  const int wm = wave >> 1, wn = wave & 1;
  const int kq = lane >> 4, lc = lane & 15;
  const float s2 = fmaxf((float)(sums[0] * (1.0 / 4194304.0)), EPSQ);
#pragma unroll
  for (int ti = 0; ti < 4; ++ti) {
#pragma unroll
    for (int r = 0; r < 4; ++r) {
      const int crow = bm * 128 + wm * 64 + ti * 16 + kq * 4 + r;
      const float dqh = fmaxf(rowmax[crow], EPSQ) * (1.f / 127.f);
      const float f = s2 * dqh;
#pragma unroll
      for (int tj = 0; tj < 4; ++tj) {
        const int gcol = bn * 128 + wn * 64 + tj * 16 + lc;
        OUT[(size_t)crow * 1024 + gcol] = (float)acc[ti][tj][r] * f;
      }
    }
  }
}

// ---------------- launcher ----------------
extern "C" void kernel_launch(void* const* d_in, const int* in_sizes, int n_in,
                              void* d_out, int out_size, void* d_ws, size_t ws_size,
                              hipStream_t stream) {
  const float* X  = (const float*)d_in[0];  // [16384][1024] fp32
  const float* W1 = (const float*)d_in[1];  // [4096][1024]  fp32
  const float* W2 = (const float*)d_in[2];  // [1024][4096]  fp32
  float* OUT = (float*)d_out;               // [16384][1024] fp32 (64 MB)

  char* ws = (char*)d_ws;
  // Fixed-footprint region: 11 MB misc + 64 MB full HQ = 75 MB
  signed char* W1Q = (signed char*)(ws);                            // 4 MB
  signed char* W2Q = (signed char*)(ws + (4u << 20));               // 4 MB
  float* DQX       = (float*)(ws + (8u << 20));                     // 64 KB
  float* ROWMAX    = (float*)(ws + (8u << 20) + 65536);             // 64 KB
  double* SUMS     = (double*)(ws + (8u << 20) + 131072);           // 16 B
  float* MBLK      = (float*)(ws + (9u << 20));                     // 2 MB [16384][32]
  signed char* HQ  = (signed char*)(ws + (11u << 20));              // 64 MB (FULL 16384x4096)
  const size_t fixed = 75u << 20;
  short* HS = (short*)(ws + fixed);                                 // R*8192 B (chunk int16 h)

  // XQ (16384x1024 i8 = 16 MB) aliases the TOP 16 MB of fp32 d_out (64 MB).
  // OUT is written ONLY by the single final gemm2 launch, which runs after every
  // gemm1 (all XQ reads) has completed in stream order — strictly
  // read-then-overwrite. OUT writes re-cover all 64 MB (poison-safe).
  signed char* XQ = (signed char*)((char*)d_out + 50331648ull);

  // Pick largest row-chunk R for the int16 HS scratch: fixed + R*8192 bytes.
  int R = 128;
  const int cands[8] = {16384, 8192, 4096, 2048, 1024, 512, 256, 128};
  for (int i = 0; i < 8; ++i) {
    if (fixed + (size_t)cands[i] * 8192ull <= ws_size) { R = cands[i]; break; }
  }

  hipLaunchKernelGGL(k_init, dim3(64), dim3(256), 0, stream, ROWMAX, SUMS);
  hipLaunchKernelGGL(k_absmean2, dim3(4096), dim3(256), 0, stream, W1, W2, SUMS);
  hipLaunchKernelGGL(k_quantw2, dim3(4096), dim3(256), 0, stream, W1, W2, W1Q, W2Q, SUMS);
  hipLaunchKernelGGL(k_quantx, dim3(16384), dim3(256), 0, stream, X, XQ, DQX);

  const int nchunk = 16384 / R;
  for (int c = 0; c < nchunk; ++c) {
    const int row0 = c * R;
    hipLaunchKernelGGL(k_gemm1, dim3(R / 128, 32), dim3(256), 0, stream,
                       XQ + (size_t)row0 * 1024, W1Q, DQX + row0, SUMS,
                       HS, MBLK + (size_t)row0 * 32, ROWMAX + row0);
    hipLaunchKernelGGL(k_quanth, dim3(R * 2), dim3(256), 0, stream,
                       HS, MBLK + (size_t)row0 * 32, ROWMAX + row0,
                       HQ + (size_t)row0 * 4096);
  }
  // Single full-size GEMM2: grid 1024 wgs.
  hipLaunchKernelGGL(k_gemm2, dim3(128, 8), dim3(256), 0, stream,
                     HQ, W2Q, ROWMAX, SUMS + 1, OUT);
}

// Round 4
// 418.534 us; speedup vs baseline: 1.0856x; 1.0822x over previous
//
#include <hip/hip_runtime.h>
#include <hip/hip_bf16.h>
#include <cstdint>
#include <cmath>

// ---------------- types / helpers ----------------
typedef int intx4 __attribute__((ext_vector_type(4)));
typedef short shortx8 __attribute__((ext_vector_type(8)));

#define EPSQ 1e-5f

// async global->LDS, 16B per lane. LDS dest = wave-uniform base + lane*16.
__device__ __forceinline__ void async16(const void* g, void* l) {
  __builtin_amdgcn_global_load_lds(
      (const __attribute__((address_space(1))) unsigned int*)(uintptr_t)g,
      (__attribute__((address_space(3))) unsigned int*)(unsigned int)(uintptr_t)l,
      16, 0, 0);
}

__device__ __forceinline__ int q8(float v, float scale, float lo, float hi) {
  return (int)fminf(fmaxf(rintf(v * scale), lo), hi);
}

// Branchless exact-GELU via Abramowitz-Stegun 7.1.26 rational erf.
__device__ __forceinline__ float fast_gelu(float y) {
  const float t = y * 0.70710678118654752f;
  const float x = fabsf(t);
  const float u = __builtin_amdgcn_rcpf(__builtin_fmaf(0.3275911f, x, 1.0f));
  float p = __builtin_fmaf(1.061405429f, u, -1.453152027f);
  p = __builtin_fmaf(p, u, 1.421413741f);
  p = __builtin_fmaf(p, u, -0.284496736f);
  p = __builtin_fmaf(p, u, 0.254829592f);
  p = p * u;
  const float e = __expf(-x * x);
  const float erf_abs = __builtin_fmaf(-p, e, 1.0f);
  const float erf_t = copysignf(erf_abs, t);
  return 0.5f * y * (1.0f + erf_t);
}

// ---------------- init ----------------
__global__ void k_init(float* rowmax, double* sums) {
  int i = blockIdx.x * 256 + threadIdx.x;
  if (i < 16384) rowmax[i] = 0.0f;
  if (i < 2) sums[i] = 0.0;
}

// ---------------- abs-sum of 2x 4194304 fp32 (-> fp64 acc), both weights ----------
__global__ __launch_bounds__(256) void k_absmean2(const float* __restrict__ W1,
                                                  const float* __restrict__ W2,
                                                  double* __restrict__ sums) {
  __shared__ double wsum[4];
  const int tid = threadIdx.x;
  const int which = blockIdx.x >> 11;                 // 0: W1, 1: W2
  const float* __restrict__ W = which ? W2 : W1;
  const size_t base = ((size_t)(blockIdx.x & 2047) * 256 + tid) * 8;
  float4 a = *(const float4*)(W + base);
  float4 b = *(const float4*)(W + base + 4);
  float s = fabsf(a.x) + fabsf(a.y) + fabsf(a.z) + fabsf(a.w) +
            fabsf(b.x) + fabsf(b.y) + fabsf(b.z) + fabsf(b.w);
  double d = (double)s;
#pragma unroll
  for (int i = 1; i < 64; i <<= 1) d += __shfl_xor(d, i);
  const int lane = tid & 63, wave = tid >> 6;
  if (lane == 0) wsum[wave] = d;
  __syncthreads();
  if (tid == 0) atomicAdd(sums + which, wsum[0] + wsum[1] + wsum[2] + wsum[3]);
}

// ---------------- ternary weight quant (fp32 in) -> int8 {-1,0,1}, both weights ----
__global__ __launch_bounds__(256) void k_quantw2(const float* __restrict__ W1,
                                                 const float* __restrict__ W2,
                                                 signed char* __restrict__ W1Q,
                                                 signed char* __restrict__ W2Q,
                                                 const double* __restrict__ sums) {
  const int which = blockIdx.x >> 11;
  const float* __restrict__ W = which ? W2 : W1;
  signed char* __restrict__ WQ = which ? W2Q : W1Q;
  const float s = fmaxf((float)(sums[which] * (1.0 / 4194304.0)), EPSQ);
  const float inv_s = 1.0f / s;
  const size_t base = ((size_t)(blockIdx.x & 2047) * 256 + threadIdx.x) * 8;
  float4 a = *(const float4*)(W + base);
  float4 b = *(const float4*)(W + base + 4);
  float v[8] = {a.x, a.y, a.z, a.w, b.x, b.y, b.z, b.w};
  unsigned int lo = 0, hi = 0;
#pragma unroll
  for (int j = 0; j < 4; ++j) {
    lo |= ((unsigned int)(q8(v[j], inv_s, -1.f, 1.f) & 0xff)) << (8 * j);
    hi |= ((unsigned int)(q8(v[4 + j], inv_s, -1.f, 1.f) & 0xff)) << (8 * j);
  }
  uint2 o; o.x = lo; o.y = hi;
  *(uint2*)(WQ + base) = o;
}

// ---------------- per-token int8 act quant of x (fp32 in, 1024/row) ----------------
__global__ __launch_bounds__(256) void k_quantx(const float* __restrict__ X,
                                                signed char* __restrict__ XQ,
                                                float* __restrict__ dqx) {
  __shared__ float wmax[4];
  const int row = blockIdx.x, tid = threadIdx.x;
  const size_t base = (size_t)row * 1024 + tid * 4;
  float4 a = *(const float4*)(X + base);
  float m = fmaxf(fmaxf(fabsf(a.x), fabsf(a.y)), fmaxf(fabsf(a.z), fabsf(a.w)));
#pragma unroll
  for (int i = 1; i < 64; i <<= 1) m = fmaxf(m, __shfl_xor(m, i));
  const int lane = tid & 63, wave = tid >> 6;
  if (lane == 0) wmax[wave] = m;
  __syncthreads();
  m = fmaxf(fmaxf(wmax[0], wmax[1]), fmaxf(wmax[2], wmax[3]));
  m = fmaxf(m, EPSQ);
  const float scale = 127.f / m;
  if (tid == 0) dqx[row] = m * (1.f / 127.f);
  unsigned int p = ((unsigned int)(q8(a.x, scale, -128.f, 127.f) & 0xff)) |
                   ((unsigned int)(q8(a.y, scale, -128.f, 127.f) & 0xff) << 8) |
                   ((unsigned int)(q8(a.z, scale, -128.f, 127.f) & 0xff) << 16) |
                   ((unsigned int)(q8(a.w, scale, -128.f, 127.f) & 0xff) << 24);
  *(unsigned int*)(XQ + base) = p;
}

// ---------------- 256x256 pipelined GEMM mainloop ----------------------------------
// C[256x256] = A[256xK] * B[256xK]^T, int8 -> int32 exact (mfma_i32_16x16x64_i8).
// 512 threads = 8 waves (2 M x 4 N); per-wave output 128x64 = 8x4 fragments.
// K-tile = 64 bytes. LDS ring of 4 slots x (A 16KB + B 16KB) = 128 KB.
// Staging runs 2 tiles ahead: per-tile wait = s_waitcnt vmcnt(8) (never 0 in
// steady state); raw s_barrier (NOT __syncthreads -> would drain vmcnt(0)).
// Ledger: entering tile t, vmcnt(8) retires tile t (t+1,t+2 in flight, 4 loads
// each); barrier => all waves' loads for t landed; then issue t+3 into slot
// (t-1)&3 whose reads completed before this barrier (lgkmcnt before MFMA).
// Swizzle: phys granule16 = logical ^ ((row>>1)&3), applied to BOTH the global
// source (staging) and the ds_read offset -> <=2-way bank conflict per phase.
template <int KB>
__device__ __forceinline__ void gemm_mainloop256(const signed char* __restrict__ A,
                                                 const signed char* __restrict__ B,
                                                 int bm, int bn, int tid, char* lds,
                                                 intx4 (&acc)[8][4]) {
  const int wave = tid >> 6, lane = tid & 63;
  const int wm = wave >> 2, wn = wave & 3;   // 2 x 4 wave grid
  const int kq = lane >> 4, lc = lane & 15;
  constexpr int NT = KB / 64;                // K-tiles

  // staging descriptors: 4 gload_lds rounds/thread/tile. rounds 0-1 = A rows,
  // rounds 2-3 = B rows. flat n = i*512+tid; r = (n&1023)>>2, g_phys = n&3.
  size_t goff[4];
  int ldsbase[4];  // wave-uniform LDS base (HW adds lane*16)
#pragma unroll
  for (int i = 0; i < 4; ++i) {
    const int n = i * 512 + tid;
    const int m = n & 1023;
    const int r = m >> 2, g = m & 3;
    const int gl = g ^ ((r >> 1) & 3);       // pre-swizzled global granule
    const int rowbase = ((i < 2) ? bm : bn) * 256 + r;
    goff[i] = (size_t)rowbase * KB + gl * 16;
    ldsbase[i] = (i * 512 + wave * 64) * 16; // == n*16 - lane*16
  }

  // fragment ds_read offsets (within a slot)
  int aoff[8], boff[4];
#pragma unroll
  for (int mi = 0; mi < 8; ++mi) {
    const int r = wm * 128 + mi * 16 + lc;
    aoff[mi] = r * 64 + ((kq ^ ((r >> 1) & 3)) << 4);
  }
#pragma unroll
  for (int ni = 0; ni < 4; ++ni) {
    const int r = wn * 64 + ni * 16 + lc;
    boff[ni] = 16384 + r * 64 + ((kq ^ ((r >> 1) & 3)) << 4);
  }

#pragma unroll
  for (int mi = 0; mi < 8; ++mi)
#pragma unroll
    for (int ni = 0; ni < 4; ++ni) {
      intx4 z = {0, 0, 0, 0};
      acc[mi][ni] = z;
    }

  // prologue: stage tiles 0,1,2
#pragma unroll
  for (int t = 0; t < 3; ++t) {
    char* lslot = lds + (t & 3) * 32768;
    const size_t k0 = (size_t)t * 64;
#pragma unroll
    for (int i = 0; i < 4; ++i)
      async16(((i < 2) ? A : B) + goff[i] + k0, lslot + ldsbase[i]);
  }

  for (int t = 0; t < NT; ++t) {
    if (t + 2 < NT)      asm volatile("s_waitcnt vmcnt(8)" ::: "memory");
    else if (t + 1 < NT) asm volatile("s_waitcnt vmcnt(4)" ::: "memory");
    else                 asm volatile("s_waitcnt vmcnt(0)" ::: "memory");
    __builtin_amdgcn_s_barrier();
    __builtin_amdgcn_sched_barrier(0);
    if (t + 3 < NT) {
      char* lslot = lds + ((t + 3) & 3) * 32768;
      const size_t k0 = (size_t)(t + 3) * 64;
#pragma unroll
      for (int i = 0; i < 4; ++i)
        async16(((i < 2) ? A : B) + goff[i] + k0, lslot + ldsbase[i]);
    }
    char* lslot = lds + (t & 3) * 32768;
    intx4 af[8], bf[4];
#pragma unroll
    for (int mi = 0; mi < 8; ++mi) af[mi] = *(const intx4*)(lslot + aoff[mi]);
#pragma unroll
    for (int ni = 0; ni < 4; ++ni) bf[ni] = *(const intx4*)(lslot + boff[ni]);
    __builtin_amdgcn_s_setprio(1);
#pragma unroll
    for (int mi = 0; mi < 8; ++mi)
#pragma unroll
      for (int ni = 0; ni < 4; ++ni)
        acc[mi][ni] =
            __builtin_amdgcn_mfma_i32_16x16x64_i8(af[mi], bf[ni], acc[mi][ni], 0, 0, 0);
    __builtin_amdgcn_s_setprio(0);
  }
}

// ---------------- GEMM1 + dequant + exact GELU + int16 block-scaled h store --------
// h stored as round(h*32767/m_blk) int16; m_blk = per-(row, 256-col-block) max|h|.
__global__ __launch_bounds__(512, 2) void k_gemm1(const signed char* __restrict__ A,
                                                  const signed char* __restrict__ B,
                                                  const float* __restrict__ dqx,
                                                  const double* __restrict__ sums,
                                                  short* __restrict__ HS,
                                                  float* __restrict__ mblk,
                                                  float* __restrict__ rowmax) {
  __shared__ __attribute__((aligned(16))) char lds[131072];
  const int tid = threadIdx.x;
  const int bm = blockIdx.x, bn = blockIdx.y;

  intx4 acc[8][4];
  gemm_mainloop256<1024>(A, B, bm, bn, tid, lds, acc);

  const int wave = tid >> 6, lane = tid & 63;
  const int wm = wave >> 2, wn = wave & 3;
  const int kq = lane >> 4, lc = lane & 15;
  const float s1 = fmaxf((float)(sums[0] * (1.0 / 4194304.0)), EPSQ);

  __syncthreads();               // mainloop fully done; reuse ring LDS for smax
  float* smax = (float*)lds;
  if (tid < 256) smax[tid] = 0.0f;
  __syncthreads();

  // pass 1: dequant + GELU, stash h bits back into acc; per-row block max via
  // 16-lane shuffle reduce (lanes sharing kq share the row), then one atomic.
#pragma unroll
  for (int mi = 0; mi < 8; ++mi) {
#pragma unroll
    for (int r = 0; r < 4; ++r) {
      const int lrow = wm * 128 + mi * 16 + kq * 4 + r;
      const int crow = bm * 256 + lrow;
      const float f = s1 * dqx[crow];
      float mx = 0.f;
#pragma unroll
      for (int ni = 0; ni < 4; ++ni) {
        float y = (float)acc[mi][ni][r] * f;
        float h = fast_gelu(y);
        acc[mi][ni][r] = (int)__float_as_uint(h);
        mx = fmaxf(mx, fabsf(h));
      }
#pragma unroll
      for (int s = 1; s < 16; s <<= 1) mx = fmaxf(mx, __shfl_xor(mx, s));
      if (lc == 0) atomicMax((unsigned int*)&smax[lrow], __float_as_uint(mx));
    }
  }
  __syncthreads();
  if (tid < 256) {
    mblk[(size_t)(bm * 256 + tid) * 16 + bn] = smax[tid];
    atomicMax((unsigned int*)&rowmax[bm * 256 + tid], __float_as_uint(smax[tid]));
  }

  // pass 2: int16 block-scaled store
#pragma unroll
  for (int mi = 0; mi < 8; ++mi) {
#pragma unroll
    for (int r = 0; r < 4; ++r) {
      const int lrow = wm * 128 + mi * 16 + kq * 4 + r;
      const int crow = bm * 256 + lrow;
      const float sc = 32767.0f / fmaxf(smax[lrow], 1e-30f);
#pragma unroll
      for (int ni = 0; ni < 4; ++ni) {
        const int gcol = bn * 256 + wn * 64 + ni * 16 + lc;
        float h = __uint_as_float((unsigned int)acc[mi][ni][r]);
        int v = (int)fminf(fmaxf(rintf(h * sc), -32767.f), 32767.f);
        HS[(size_t)crow * 4096 + gcol] = (short)v;
      }
    }
  }
}

// ---------------- requantize h: int16 (block scale) -> int8 (global row scale) -----
__global__ __launch_bounds__(256) void k_quanth(const short* __restrict__ HS,
                                                const float* __restrict__ mblk,
                                                const float* __restrict__ rowmax,
                                                signed char* __restrict__ HQ) {
  const size_t gid = (size_t)blockIdx.x * 256 + threadIdx.x;
  const size_t base = gid * 8;              // 8 int16 per thread, one 256-col block
  const int row = (int)(base >> 12);        // 4096 per row
  const int blk = (int)((base >> 8) & 15);  // 256-col block index
  const float m = fmaxf(rowmax[row], EPSQ);
  const float fb = mblk[(size_t)row * 16 + blk] * (127.0f / 32767.0f) / m;
  shortx8 s = *(const shortx8*)(HS + base);
  unsigned int lo = 0, hi = 0;
#pragma unroll
  for (int j = 0; j < 4; ++j) {
    lo |= ((unsigned int)(q8((float)s[j], fb, -128.f, 127.f) & 0xff)) << (8 * j);
    hi |= ((unsigned int)(q8((float)s[4 + j], fb, -128.f, 127.f) & 0xff)) << (8 * j);
  }
  uint2 o; o.x = lo; o.y = hi;
  *(uint2*)(HQ + base) = o;
}

// ---------------- GEMM2 + dequant -> fp32 out (global rows, single launch) ----------
__global__ __launch_bounds__(512, 2) void k_gemm2(const signed char* __restrict__ A,
                                                  const signed char* __restrict__ B,
                                                  const float* __restrict__ rowmax,
                                                  const double* __restrict__ sums,
                                                  float* __restrict__ OUT) {
  __shared__ __attribute__((aligned(16))) char lds[131072];
  const int tid = threadIdx.x;
  const int bm = blockIdx.x, bn = blockIdx.y;

  intx4 acc[8][4];
  gemm_mainloop256<4096>(A, B, bm, bn, tid, lds, acc);

  const int wave = tid >> 6, lane = tid & 63;
  const int wm = wave >> 2, wn = wave & 3;
  const int kq = lane >> 4, lc = lane & 15;
  const float s2 = fmaxf((float)(sums[0] * (1.0 / 4194304.0)), EPSQ);
#pragma unroll
  for (int mi = 0; mi < 8; ++mi) {
#pragma unroll
    for (int r = 0; r < 4; ++r) {
      const int crow = bm * 256 + wm * 128 + mi * 16 + kq * 4 + r;
      const float dqh = fmaxf(rowmax[crow], EPSQ) * (1.f / 127.f);
      const float f = s2 * dqh;
#pragma unroll
      for (int ni = 0; ni < 4; ++ni) {
        const int gcol = bn * 256 + wn * 64 + ni * 16 + lc;
        OUT[(size_t)crow * 1024 + gcol] = (float)acc[mi][ni][r] * f;
      }
    }
  }
}

// ---------------- launcher ----------------
extern "C" void kernel_launch(void* const* d_in, const int* in_sizes, int n_in,
                              void* d_out, int out_size, void* d_ws, size_t ws_size,
                              hipStream_t stream) {
  const float* X  = (const float*)d_in[0];  // [16384][1024] fp32
  const float* W1 = (const float*)d_in[1];  // [4096][1024]  fp32
  const float* W2 = (const float*)d_in[2];  // [1024][4096]  fp32
  float* OUT = (float*)d_out;               // [16384][1024] fp32 (64 MB)

  char* ws = (char*)d_ws;
  // Fixed-footprint region: 10 MB misc + 64 MB full HQ = 74 MB
  signed char* W1Q = (signed char*)(ws);                            // 4 MB
  signed char* W2Q = (signed char*)(ws + (4u << 20));               // 4 MB
  float* DQX       = (float*)(ws + (8u << 20));                     // 64 KB
  float* ROWMAX    = (float*)(ws + (8u << 20) + 65536);             // 64 KB
  double* SUMS     = (double*)(ws + (8u << 20) + 131072);           // 16 B
  float* MBLK      = (float*)(ws + (9u << 20));                     // 1 MB [16384][16]
  signed char* HQ  = (signed char*)(ws + (10u << 20));              // 64 MB (FULL)
  const size_t fixed = 74u << 20;
  short* HS = (short*)(ws + fixed);                                 // R*8192 B

  // XQ (16384x1024 i8 = 16 MB) aliases the TOP 16 MB of fp32 d_out (64 MB).
  // OUT is written ONLY by the final gemm2 launch, after all gemm1 XQ reads
  // (stream order) — strictly read-then-overwrite; OUT re-covers all 64 MB.
  signed char* XQ = (signed char*)((char*)d_out + 50331648ull);

  // Row-chunk R (multiple of 256) for the int16 HS scratch.
  int R = 256;
  const int cands[7] = {16384, 8192, 4096, 2048, 1024, 512, 256};
  for (int i = 0; i < 7; ++i) {
    if (fixed + (size_t)cands[i] * 8192ull <= ws_size) { R = cands[i]; break; }
  }

  hipLaunchKernelGGL(k_init, dim3(64), dim3(256), 0, stream, ROWMAX, SUMS);
  hipLaunchKernelGGL(k_absmean2, dim3(4096), dim3(256), 0, stream, W1, W2, SUMS);
  hipLaunchKernelGGL(k_quantw2, dim3(4096), dim3(256), 0, stream, W1, W2, W1Q, W2Q, SUMS);
  hipLaunchKernelGGL(k_quantx, dim3(16384), dim3(256), 0, stream, X, XQ, DQX);

  const int nchunk = 16384 / R;
  for (int c = 0; c < nchunk; ++c) {
    const int row0 = c * R;
    hipLaunchKernelGGL(k_gemm1, dim3(R / 256, 16), dim3(512), 0, stream,
                       XQ + (size_t)row0 * 1024, W1Q, DQX + row0, SUMS,
                       HS, MBLK + (size_t)row0 * 16, ROWMAX + row0);
    hipLaunchKernelGGL(k_quanth, dim3(R * 2), dim3(256), 0, stream,
                       HS, MBLK + (size_t)row0 * 16, ROWMAX + row0,
                       HQ + (size_t)row0 * 4096);
  }
  // Single full-size GEMM2: grid (64,4) = 256 wgs (1 per CU at 128KB LDS).
  hipLaunchKernelGGL(k_gemm2, dim3(64, 4), dim3(512), 0, stream,
                     HQ, W2Q, ROWMAX, SUMS + 1, OUT);
}